// Round 6
// baseline (7208.718 us; speedup 1.0000x reference)
//
#include <hip/hip_runtime.h>
#include <hip/hip_fp16.h>
#include <cstdint>
#include <cstddef>

// ---------------------------------------------------------------------------
// CNN (conv1+pool, conv2+pool) -> seq [256][256][32]
// NTM scan: 128 blocks x 1024 threads, 2 batch/block, 1 block/CU.
// OVERLAPPED structure per step i (2 barriers):
//   chain A (waves 0..13): zA = Wx*x_i + Wh*h_{i-1}   (144 fp16 k-pairs, dot2)
//   chain B (waves 14,15; one per batch): FULL serial NTM chain for step i-1
//     wave-locally: head GEMM -> addressing (both heads in 32-lane halves)
//     -> fused read+erase/add -> reads_{i-1} -> zR = Wr*reads
//   B1; post: z_i = sum(zA)+zR+bias -> LSTM -> h_i; x_{i+1} prefetch; B2.
// ci slot order (fp16 pairs): [x:0..15][h:16..143][reads:144..153][pad..159]
// ---------------------------------------------------------------------------

#define MW    20
#define NLOC  128
#define ZC    1024
#define PC    92
#define CLIPV 20.0f

__device__ __forceinline__ float sigmoidf_(float x) { return 1.0f / (1.0f + expf(-x)); }
__device__ __forceinline__ float softplusf_(float x) { return log1pf(expf(x)); }

__device__ __forceinline__ float dot2f(uint32_t w, uint32_t a, float c) {
    asm("v_dot2_f32_f16 %0, %1, %2, %0" : "+v"(c) : "v"(w), "v"(a));
    return c;
}
__device__ __forceinline__ void wave_lds_fence() {
    asm volatile("s_waitcnt lgkmcnt(0)" ::: "memory");
    __builtin_amdgcn_sched_barrier(0);
}

// weight row r (ci slot order) -> source
__device__ __forceinline__ float wval2(const float* wx, const float* wh, int r, int col) {
    if (r < 32)  return wx[r * ZC + col];                 // x rows
    if (r < 288) return wh[(r - 32) * ZC + col];          // h rows
    if (r < 308) return wx[(32 + (r - 288)) * ZC + col];  // reads rows
    return 0.0f;
}
__device__ __forceinline__ uint32_t packpr(const float* wx, const float* wh, int pr, int col) {
    __half2 h = __floats2half2_rn(wval2(wx, wh, 2 * pr, col), wval2(wx, wh, 2 * pr + 1, col));
    return *reinterpret_cast<uint32_t*>(&h);
}

// WG: u32 idx = (pr*256 + cc)*4 + m -> col = 4cc+m, pairs 0..159.
// hw2T: [col][128 u-pairs] u32 (transposed head weights).
__global__ __launch_bounds__(256) void prep_pack(const float* __restrict__ wx,
                                                 const float* __restrict__ wh,
                                                 const float* __restrict__ hw,
                                                 uint32_t* __restrict__ WG,      // [160][256][4]
                                                 uint32_t* __restrict__ hw2T) {  // [92][128]
    int idx = blockIdx.x * 256 + threadIdx.x;
    if (idx < 163840) {
        int m = idx & 3, cc = (idx >> 2) & 255, pr = idx >> 10;
        WG[idx] = packpr(wx, wh, pr, cc * 4 + m);
    } else if (idx < 163840 + 11776) {
        int q = idx - 163840;
        int col = q >> 7, up = q & 127;
        __half2 h = __floats2half2_rn(hw[(2 * up) * PC + col], hw[(2 * up + 1) * PC + col]);
        hw2T[q] = *reinterpret_cast<uint32_t*>(&h);
    }
}

// conv1 3x3 (1->16) SAME + relu + maxpool2
__global__ __launch_bounds__(256) void conv1_pool(const float* __restrict__ in,
                                                  const float* __restrict__ w,
                                                  const float* __restrict__ bias,
                                                  float* __restrict__ out) {
    int idx = blockIdx.x * 256 + threadIdx.x;
    if (idx >= 256 * 32 * 32 * 16) return;
    int c = idx & 15, x = (idx >> 4) & 31, y = (idx >> 9) & 31, b = idx >> 14;
    const float* inb = in + (size_t)b * 4096;
    float bv = bias[c];
    float mx = 0.0f;
    #pragma unroll
    for (int dy = 0; dy < 2; ++dy)
    #pragma unroll
    for (int dx = 0; dx < 2; ++dx) {
        int oy = 2 * y + dy, ox = 2 * x + dx;
        float s = bv;
        #pragma unroll
        for (int ky = 0; ky < 3; ++ky) {
            int iy = oy + ky - 1;
            if (iy < 0 || iy > 63) continue;
            #pragma unroll
            for (int kx = 0; kx < 3; ++kx) {
                int ix = ox + kx - 1;
                if (ix < 0 || ix > 63) continue;
                s = fmaf(inb[iy * 64 + ix], w[(ky * 3 + kx) * 16 + c], s);
            }
        }
        mx = fmaxf(mx, fmaxf(s, 0.0f));
    }
    out[idx] = mx;
}

// conv2 3x3 (16->32) SAME + relu + maxpool2 (weights hoisted per tap, f4 inputs)
__global__ __launch_bounds__(256) void conv2_pool(const float* __restrict__ p1,
                                                  const float* __restrict__ w,
                                                  const float* __restrict__ bias,
                                                  float* __restrict__ seq) {
    int idx = blockIdx.x * 256 + threadIdx.x;
    if (idx >= 256 * 16 * 16 * 32) return;
    int c = idx & 31, x = (idx >> 5) & 15, y = (idx >> 9) & 15, b = idx >> 13;
    const float* pb = p1 + (size_t)b * (32 * 32 * 16);
    float bv = bias[c];
    float acc[4] = {bv, bv, bv, bv};
    #pragma unroll
    for (int ky = 0; ky < 3; ++ky)
    #pragma unroll
    for (int kx = 0; kx < 3; ++kx) {
        float w16[16];
        #pragma unroll
        for (int i = 0; i < 16; ++i) w16[i] = w[((ky * 3 + kx) * 16 + i) * 32 + c];
        #pragma unroll
        for (int dy = 0; dy < 2; ++dy)
        #pragma unroll
        for (int dx = 0; dx < 2; ++dx) {
            int iy = 2 * y + dy + ky - 1, ix = 2 * x + dx + kx - 1;
            if (iy < 0 || iy > 31 || ix < 0 || ix > 31) continue;
            const float4* pin4 = (const float4*)(pb + (iy * 32 + ix) * 16);
            float4 v0 = pin4[0], v1 = pin4[1], v2 = pin4[2], v3 = pin4[3];
            int a = dy * 2 + dx;
            acc[a] = fmaf(v0.x, w16[0], acc[a]);  acc[a] = fmaf(v0.y, w16[1], acc[a]);
            acc[a] = fmaf(v0.z, w16[2], acc[a]);  acc[a] = fmaf(v0.w, w16[3], acc[a]);
            acc[a] = fmaf(v1.x, w16[4], acc[a]);  acc[a] = fmaf(v1.y, w16[5], acc[a]);
            acc[a] = fmaf(v1.z, w16[6], acc[a]);  acc[a] = fmaf(v1.w, w16[7], acc[a]);
            acc[a] = fmaf(v2.x, w16[8], acc[a]);  acc[a] = fmaf(v2.y, w16[9], acc[a]);
            acc[a] = fmaf(v2.z, w16[10], acc[a]); acc[a] = fmaf(v2.w, w16[11], acc[a]);
            acc[a] = fmaf(v3.x, w16[12], acc[a]); acc[a] = fmaf(v3.y, w16[13], acc[a]);
            acc[a] = fmaf(v3.z, w16[14], acc[a]); acc[a] = fmaf(v3.w, w16[15], acc[a]);
        }
    }
    float mx = 0.0f;
    #pragma unroll
    for (int a = 0; a < 4; ++a) mx = fmaxf(mx, acc[a]);
    seq[idx] = mx;
}

// ---------------------------------------------------------------------------
// Persistent NTM scan with chainA/chainB overlap.
// ---------------------------------------------------------------------------
__global__ __launch_bounds__(1024, 4) void ntm_scan6(
    const float* __restrict__ seq,
    const uint32_t* __restrict__ WG,
    const uint32_t* __restrict__ hw2T,
    const float* __restrict__ lb,
    const float* __restrict__ hb,
    const float* __restrict__ ow,
    const float* __restrict__ ob,
    const float* __restrict__ dw,
    const float* __restrict__ db,
    float* __restrict__ out)          // [256][2]
{
    __shared__ uint4 Wl4[16 * 256];                   // 65536 B: x-pairs 0..15
    __shared__ float zpartA[7][2][ZC];                // 57344 B
    __shared__ float zRs[2][ZC];                      // 8192 B
    __shared__ __align__(16) _Float16 ci2h[2][320];   // 1280 B
    __shared__ float Msh[2][MW][132];                 // 21120 B
    __shared__ float wprev[2][2][NLOC];               // 2048 B
    __shared__ float psA[2][PC];                      // 736 B
    __shared__ float rds[2][MW];                      // 160 B
    __shared__ float o8[2][8];                        // 64 B
    // total 156480 B

    const int t = threadIdx.x;
    const int bs0 = blockIdx.x * 2;
    const int w = t >> 6;
    const int l = t & 63;
    const uint4* WG4 = (const uint4*)WG;
    const uint4* hw4 = (const uint4*)hw2T;

    // ---- stage x-pair weights to LDS (pairs 0..15 are first 4096 uint4) ----
    for (int i = t; i < 4096; i += 1024) Wl4[i] = WG4[i];

    // ---- init state ----
    for (int i = t; i < 2 * 320; i += 1024) {
        int b = i / 320, k = i - b * 320;
        _Float16 v;
        if (k < 32)       v = (_Float16)seq[(size_t)(bs0 + b) * 8192 + k];  // x_0
        else if (k < 288) v = (_Float16)0.0f;                               // h
        else if (k < 308) v = (_Float16)1e-6f;                              // reads
        else              v = (_Float16)0.0f;                               // pad
        ci2h[b][k] = v;
    }
    for (int i = t; i < 2 * MW * 132; i += 1024) {
        int b = i / (MW * 132), r = i - b * (MW * 132);
        Msh[b][r / 132][r - (r / 132) * 132] = 1e-6f;
    }
    if (t < 512) {
        int b = t >> 8, r = t & 255;
        wprev[b][r >> 7][r & 127] = 1.0f / 128.0f;
    }
    float c_reg = 0.0f;   // cell state: thread t<512 owns (b=t>>8, u=t&255)
    __syncthreads();

    const uint32_t* ci2u0 = (const uint32_t*)&ci2h[0][0];
    const uint32_t* ci2u1 = (const uint32_t*)&ci2h[1][0];

    // ======= chain B body (one wave, one batch): full NTM chain for a step ==
    auto chainB = [&](int bIdx, bool isInit, bool doZR, bool isTail) {
        float r[20];
        if (isInit) {
            #pragma unroll
            for (int wi = 0; wi < 20; ++wi) r[wi] = 1e-6f;
        } else {
            // ---- P3: p = clip(h @ head_w + head_b) ; lane l -> cols l, l+64 ----
            const uint32_t* hu = (bIdx ? ci2u1 : ci2u0) + 16;   // 128 h-pairs
            const int col2 = (l < 28) ? (l + 64) : 64;
            float sA = 0.0f, sB = 0.0f;
            #pragma unroll
            for (int ch = 0; ch < 8; ++ch) {
                uint4 h0 = *(const uint4*)(hu + ch * 16);
                uint4 h1 = *(const uint4*)(hu + ch * 16 + 4);
                uint4 h2 = *(const uint4*)(hu + ch * 16 + 8);
                uint4 h3 = *(const uint4*)(hu + ch * 16 + 12);
                uint4 a0 = hw4[l * 32 + ch * 4],     a1 = hw4[l * 32 + ch * 4 + 1];
                uint4 a2 = hw4[l * 32 + ch * 4 + 2], a3 = hw4[l * 32 + ch * 4 + 3];
                uint4 b0 = hw4[col2 * 32 + ch * 4],     b1 = hw4[col2 * 32 + ch * 4 + 1];
                uint4 b2 = hw4[col2 * 32 + ch * 4 + 2], b3 = hw4[col2 * 32 + ch * 4 + 3];
                sA = dot2f(a0.x, h0.x, sA); sA = dot2f(a0.y, h0.y, sA);
                sA = dot2f(a0.z, h0.z, sA); sA = dot2f(a0.w, h0.w, sA);
                sA = dot2f(a1.x, h1.x, sA); sA = dot2f(a1.y, h1.y, sA);
                sA = dot2f(a1.z, h1.z, sA); sA = dot2f(a1.w, h1.w, sA);
                sA = dot2f(a2.x, h2.x, sA); sA = dot2f(a2.y, h2.y, sA);
                sA = dot2f(a2.z, h2.z, sA); sA = dot2f(a2.w, h2.w, sA);
                sA = dot2f(a3.x, h3.x, sA); sA = dot2f(a3.y, h3.y, sA);
                sA = dot2f(a3.z, h3.z, sA); sA = dot2f(a3.w, h3.w, sA);
                sB = dot2f(b0.x, h0.x, sB); sB = dot2f(b0.y, h0.y, sB);
                sB = dot2f(b0.z, h0.z, sB); sB = dot2f(b0.w, h0.w, sB);
                sB = dot2f(b1.x, h1.x, sB); sB = dot2f(b1.y, h1.y, sB);
                sB = dot2f(b1.z, h1.z, sB); sB = dot2f(b1.w, h1.w, sB);
                sB = dot2f(b2.x, h2.x, sB); sB = dot2f(b2.y, h2.y, sB);
                sB = dot2f(b2.z, h2.z, sB); sB = dot2f(b2.w, h2.w, sB);
                sB = dot2f(b3.x, h3.x, sB); sB = dot2f(b3.y, h3.y, sB);
                sB = dot2f(b3.z, h3.z, sB); sB = dot2f(b3.w, h3.w, sB);
            }
            psA[bIdx][l] = fminf(fmaxf(sA + hb[l], -CLIPV), CLIPV);
            if (l < 28) psA[bIdx][l + 64] = fminf(fmaxf(sB + hb[l + 64], -CLIPV), CLIPV);
            wave_lds_fence();

            // ---- P4: addressing; lanes 0..31 head0, 32..63 head1; n = 4j..4j+3 ----
            const int hh = l >> 5, j = l & 31, base = hh << 5;
            const int hc = hh * 26;
            float beta  = softplusf_(psA[bIdx][hc + 20]);
            float g     = sigmoidf_(psA[bIdx][hc + 21]);
            float s0r = psA[bIdx][hc + 22], s1r = psA[bIdx][hc + 23], s2r = psA[bIdx][hc + 24];
            float mS = fmaxf(s0r, fmaxf(s1r, s2r));
            float q0 = expf(s0r - mS), q1 = expf(s1r - mS), q2 = expf(s2r - mS);
            float qin = 1.0f / (q0 + q1 + q2);
            float sh0 = q0 * qin, sh1 = q1 * qin, sh2 = q2 * qin;
            float gamma = softplusf_(psA[bIdx][hc + 25]) + 1.0f;

            float kvv = (j < 20) ? tanhf(psA[bIdx][hc + j]) : 0.0f;
            float kn2 = kvv * kvv;
            #pragma unroll
            for (int o = 1; o < 32; o <<= 1) kn2 += __shfl_xor(kn2, o, 64);
            float kden = sqrtf(kn2) + 1e-8f;

            float d[4] = {0, 0, 0, 0}, m2[4] = {0, 0, 0, 0};
            #pragma unroll
            for (int wi = 0; wi < 20; ++wi) {
                float kk = __shfl(kvv, base + wi, 64);
                float4 mv = *(const float4*)&Msh[bIdx][wi][4 * j];
                d[0] = fmaf(kk, mv.x, d[0]); m2[0] = fmaf(mv.x, mv.x, m2[0]);
                d[1] = fmaf(kk, mv.y, d[1]); m2[1] = fmaf(mv.y, mv.y, m2[1]);
                d[2] = fmaf(kk, mv.z, d[2]); m2[2] = fmaf(mv.z, mv.z, m2[2]);
                d[3] = fmaf(kk, mv.w, d[3]); m2[3] = fmaf(mv.w, mv.w, m2[3]);
            }
            float x[4];
            #pragma unroll
            for (int q = 0; q < 4; ++q) x[q] = beta * (d[q] / ((sqrtf(m2[q]) + 1e-8f) * kden));
            float mx = fmaxf(fmaxf(x[0], x[1]), fmaxf(x[2], x[3]));
            #pragma unroll
            for (int o = 1; o < 32; o <<= 1) mx = fmaxf(mx, __shfl_xor(mx, o, 64));
            float e[4]; float se = 0.0f;
            #pragma unroll
            for (int q = 0; q < 4; ++q) { e[q] = expf(x[q] - mx); se += e[q]; }
            #pragma unroll
            for (int o = 1; o < 32; o <<= 1) se += __shfl_xor(se, o, 64);
            float inv = 1.0f / se;
            float4 wpv = *(const float4*)&wprev[bIdx][hh][4 * j];
            float wg[4];
            wg[0] = g * (e[0] * inv) + (1.0f - g) * wpv.x;
            wg[1] = g * (e[1] * inv) + (1.0f - g) * wpv.y;
            wg[2] = g * (e[2] * inv) + (1.0f - g) * wpv.z;
            wg[3] = g * (e[3] * inv) + (1.0f - g) * wpv.w;
            float wgm = __shfl(wg[3], base + ((j + 31) & 31), 64);
            float wgp = __shfl(wg[0], base + ((j + 1) & 31), 64);
            float wt[4];
            wt[0] = sh0 * wg[1] + sh1 * wg[0] + sh2 * wgm;
            wt[1] = sh0 * wg[2] + sh1 * wg[1] + sh2 * wg[0];
            wt[2] = sh0 * wg[3] + sh1 * wg[2] + sh2 * wg[1];
            wt[3] = sh0 * wgp  + sh1 * wg[3] + sh2 * wg[2];
            float wp[4]; float ss = 0.0f;
            #pragma unroll
            for (int q = 0; q < 4; ++q) { wp[q] = expf(gamma * logf(wt[q] + 1e-8f)); ss += wp[q]; }
            #pragma unroll
            for (int o = 1; o < 32; o <<= 1) ss += __shfl_xor(ss, o, 64);
            float rin = 1.0f / ss;
            *(float4*)&wprev[bIdx][hh][4 * j] =
                make_float4(wp[0] * rin, wp[1] * rin, wp[2] * rin, wp[3] * rin);
            wave_lds_fence();

            // ---- erase/add params (write head), kept in lanes 0..19 ----
            float evr = 0.0f, avr = 0.0f;
            if (l < 20) { evr = sigmoidf_(psA[bIdx][52 + l]); avr = tanhf(psA[bIdx][72 + l]); }

            // ---- P5: fused read-dot + erase/add; lane owns n = l, l+64 ----
            float wr0 = wprev[bIdx][0][l], wr1 = wprev[bIdx][0][l + 64];
            float ww0 = wprev[bIdx][1][l], ww1 = wprev[bIdx][1][l + 64];
            #pragma unroll
            for (int wi = 0; wi < 20; ++wi) {
                float m0 = Msh[bIdx][wi][l], m1 = Msh[bIdx][wi][l + 64];
                float s = fmaf(wr0, m0, wr1 * m1);
                #pragma unroll
                for (int o = 1; o < 64; o <<= 1) s += __shfl_xor(s, o, 64);
                float evb = __shfl(evr, wi, 64), avb = __shfl(avr, wi, 64);
                Msh[bIdx][wi][l]      = m0 * (1.0f - ww0 * evb) + ww0 * avb;
                Msh[bIdx][wi][l + 64] = m1 * (1.0f - ww1 * evb) + ww1 * avb;
                r[wi] = s;
                if (l == wi) ci2h[bIdx][288 + wi] = (_Float16)s;
            }
        }

        if (isTail) {
            if (l == 0) {
                #pragma unroll
                for (int wi = 0; wi < 20; ++wi) rds[bIdx][wi] = r[wi];
            }
        }
        if (doZR) {
            // ---- zR = Wr * reads (pairs 144..153), lane covers cols 4c4..4c4+3 ----
            uint32_t rp[10];
            #pragma unroll
            for (int q = 0; q < 10; ++q) {
                __half2 hp = __floats2half2_rn(r[2 * q], r[2 * q + 1]);
                rp[q] = *reinterpret_cast<uint32_t*>(&hp);
            }
            #pragma unroll
            for (int jj = 0; jj < 4; ++jj) {
                int c4 = l + 64 * jj;
                float a0 = 0, a1 = 0, a2 = 0, a3 = 0;
                #pragma unroll
                for (int q = 0; q < 10; ++q) {
                    uint4 wq = WG4[(144 + q) * 256 + c4];
                    a0 = dot2f(wq.x, rp[q], a0);
                    a1 = dot2f(wq.y, rp[q], a1);
                    a2 = dot2f(wq.z, rp[q], a2);
                    a3 = dot2f(wq.w, rp[q], a3);
                }
                *(float4*)&zRs[bIdx][4 * c4] = make_float4(a0, a1, a2, a3);
            }
        }
    };

    // ======================= main loop =======================
    for (int step = 0; step < 256; ++step) {
        if (w < 14) {
            // ---- chain A: zA over pairs {x 0..15, h 16..143} (+3 zero pads) ----
            const int s = t >> 7;         // kslice 0..6
            const int c7 = t & 127;       // cols 8c7..8c7+7
            float acc[2][8];
            #pragma unroll
            for (int m = 0; m < 8; ++m) { acc[0][m] = 0.0f; acc[1][m] = 0.0f; }
            if (s == 0) {
                #pragma unroll
                for (int q = 0; q < 16; ++q) {       // LDS x-pairs
                    uint4 w0 = Wl4[q * 256 + 2 * c7];
                    uint4 w1 = Wl4[q * 256 + 2 * c7 + 1];
                    uint32_t a0 = ci2u0[q], a1 = ci2u1[q];
                    acc[0][0] = dot2f(w0.x, a0, acc[0][0]); acc[0][1] = dot2f(w0.y, a0, acc[0][1]);
                    acc[0][2] = dot2f(w0.z, a0, acc[0][2]); acc[0][3] = dot2f(w0.w, a0, acc[0][3]);
                    acc[0][4] = dot2f(w1.x, a0, acc[0][4]); acc[0][5] = dot2f(w1.y, a0, acc[0][5]);
                    acc[0][6] = dot2f(w1.z, a0, acc[0][6]); acc[0][7] = dot2f(w1.w, a0, acc[0][7]);
                    acc[1][0] = dot2f(w0.x, a1, acc[1][0]); acc[1][1] = dot2f(w0.y, a1, acc[1][1]);
                    acc[1][2] = dot2f(w0.z, a1, acc[1][2]); acc[1][3] = dot2f(w0.w, a1, acc[1][3]);
                    acc[1][4] = dot2f(w1.x, a1, acc[1][4]); acc[1][5] = dot2f(w1.y, a1, acc[1][5]);
                    acc[1][6] = dot2f(w1.z, a1, acc[1][6]); acc[1][7] = dot2f(w1.w, a1, acc[1][7]);
                }
                #pragma unroll
                for (int q = 16; q < 21; ++q) {      // streamed pairs 16..20
                    uint4 w0 = WG4[q * 256 + 2 * c7];
                    uint4 w1 = WG4[q * 256 + 2 * c7 + 1];
                    uint32_t a0 = ci2u0[q], a1 = ci2u1[q];
                    acc[0][0] = dot2f(w0.x, a0, acc[0][0]); acc[0][1] = dot2f(w0.y, a0, acc[0][1]);
                    acc[0][2] = dot2f(w0.z, a0, acc[0][2]); acc[0][3] = dot2f(w0.w, a0, acc[0][3]);
                    acc[0][4] = dot2f(w1.x, a0, acc[0][4]); acc[0][5] = dot2f(w1.y, a0, acc[0][5]);
                    acc[0][6] = dot2f(w1.z, a0, acc[0][6]); acc[0][7] = dot2f(w1.w, a0, acc[0][7]);
                    acc[1][0] = dot2f(w0.x, a1, acc[1][0]); acc[1][1] = dot2f(w0.y, a1, acc[1][1]);
                    acc[1][2] = dot2f(w0.z, a1, acc[1][2]); acc[1][3] = dot2f(w0.w, a1, acc[1][3]);
                    acc[1][4] = dot2f(w1.x, a1, acc[1][4]); acc[1][5] = dot2f(w1.y, a1, acc[1][5]);
                    acc[1][6] = dot2f(w1.z, a1, acc[1][6]); acc[1][7] = dot2f(w1.w, a1, acc[1][7]);
                }
            } else {
                const int pi0 = s * 21;
                #pragma unroll
                for (int q = 0; q < 21; ++q) {
                    int pi = pi0 + q;
                    int pr = (pi < 144) ? pi : pi + 10;   // 144..146 -> zero pads 154..156
                    uint4 w0 = WG4[pr * 256 + 2 * c7];
                    uint4 w1 = WG4[pr * 256 + 2 * c7 + 1];
                    uint32_t a0 = ci2u0[pr], a1 = ci2u1[pr];
                    acc[0][0] = dot2f(w0.x, a0, acc[0][0]); acc[0][1] = dot2f(w0.y, a0, acc[0][1]);
                    acc[0][2] = dot2f(w0.z, a0, acc[0][2]); acc[0][3] = dot2f(w0.w, a0, acc[0][3]);
                    acc[0][4] = dot2f(w1.x, a0, acc[0][4]); acc[0][5] = dot2f(w1.y, a0, acc[0][5]);
                    acc[0][6] = dot2f(w1.z, a0, acc[0][6]); acc[0][7] = dot2f(w1.w, a0, acc[0][7]);
                    acc[1][0] = dot2f(w0.x, a1, acc[1][0]); acc[1][1] = dot2f(w0.y, a1, acc[1][1]);
                    acc[1][2] = dot2f(w0.z, a1, acc[1][2]); acc[1][3] = dot2f(w0.w, a1, acc[1][3]);
                    acc[1][4] = dot2f(w1.x, a1, acc[1][4]); acc[1][5] = dot2f(w1.y, a1, acc[1][5]);
                    acc[1][6] = dot2f(w1.z, a1, acc[1][6]); acc[1][7] = dot2f(w1.w, a1, acc[1][7]);
                }
            }
            #pragma unroll
            for (int b = 0; b < 2; ++b) {
                *(float4*)&zpartA[s][b][8 * c7]     = make_float4(acc[b][0], acc[b][1], acc[b][2], acc[b][3]);
                *(float4*)&zpartA[s][b][8 * c7 + 4] = make_float4(acc[b][4], acc[b][5], acc[b][6], acc[b][7]);
            }
        } else {
            chainB(w - 14, step == 0, true, false);
        }
        __syncthreads();   // B1

        // ---- post: assemble z, LSTM, x prefetch ----
        if (t < 512) {
            int b = t >> 8, u = t & 255;
            float zi = lb[u]       + zRs[b][u];
            float zf = lb[256 + u] + zRs[b][256 + u];
            float zg = lb[512 + u] + zRs[b][512 + u];
            float zo = lb[768 + u] + zRs[b][768 + u];
            #pragma unroll
            for (int q = 0; q < 7; ++q) {
                zi += zpartA[q][b][u];       zf += zpartA[q][b][256 + u];
                zg += zpartA[q][b][512 + u]; zo += zpartA[q][b][768 + u];
            }
            float cg = sigmoidf_(zf) * c_reg + sigmoidf_(zi) * tanhf(zg);
            c_reg = cg;
            ci2h[b][32 + u] = (_Float16)(sigmoidf_(zo) * tanhf(cg));
        } else if (t < 576 && step < 255) {
            int q = t - 512, b = q >> 5, cc = q & 31;
            ci2h[b][cc] = (_Float16)seq[(size_t)(bs0 + b) * 8192 + (size_t)(step + 1) * 32 + cc];
        }
        __syncthreads();   // B2
    }

    // ---- epilogue: chain B tail for step 255 (produces reads_255 -> rds) ----
    if (w >= 14) chainB(w - 14, false, false, true);
    __syncthreads();

    // ---- final NTM output head + dense + softmax ----
    if (t < 16) {
        int b = t >> 3, o = t & 7;
        float s = ob[o];
        for (int u = 0; u < 256; ++u) s = fmaf((float)ci2h[b][32 + u], ow[u * 8 + o], s);
        #pragma unroll
        for (int wi = 0; wi < 20; ++wi) s = fmaf(rds[b][wi], ow[(256 + wi) * 8 + o], s);
        o8[b][o] = fminf(fmaxf(s, -CLIPV), CLIPV);
    }
    __syncthreads();
    if (t < 2) {
        float l0 = db[0], l1 = db[1];
        #pragma unroll
        for (int k = 0; k < 8; ++k) {
            float v = o8[t][k];
            l0 = fmaf(v, dw[k * 2 + 0], l0);
            l1 = fmaf(v, dw[k * 2 + 1], l1);
        }
        float m = fmaxf(l0, l1);
        float q0 = expf(l0 - m), q1 = expf(l1 - m);
        float inv = 1.0f / (q0 + q1);
        out[(bs0 + t) * 2 + 0] = q0 * inv;
        out[(bs0 + t) * 2 + 1] = q1 * inv;
    }
}

extern "C" void kernel_launch(void* const* d_in, const int* in_sizes, int n_in,
                              void* d_out, int out_size, void* d_ws, size_t ws_size,
                              hipStream_t stream) {
    const float* inputs = (const float*)d_in[0];
    const float* c1w = (const float*)d_in[1];
    const float* c1b = (const float*)d_in[2];
    const float* c2w = (const float*)d_in[3];
    const float* c2b = (const float*)d_in[4];
    const float* lwx = (const float*)d_in[5];
    const float* lwh = (const float*)d_in[6];
    const float* lb  = (const float*)d_in[7];
    const float* hw  = (const float*)d_in[8];
    const float* hb  = (const float*)d_in[9];
    const float* ow  = (const float*)d_in[10];
    const float* ob  = (const float*)d_in[11];
    const float* dw  = (const float*)d_in[12];
    const float* db  = (const float*)d_in[13];
    float* out = (float*)d_out;

    float* ws    = (float*)d_ws;
    float* p1    = ws;                             // 4,194,304 f
    float* seq   = ws + 4194304;                   // 2,097,152 f
    uint32_t* WG    = (uint32_t*)(ws + 6291456);   // 163,840 u32
    uint32_t* hw2T  = WG + 163840;                 //  11,776 u32

    hipLaunchKernelGGL(prep_pack,  dim3(686),   dim3(256),  0, stream, lwx, lwh, hw, WG, hw2T);
    hipLaunchKernelGGL(conv1_pool, dim3(16384), dim3(256),  0, stream, inputs, c1w, c1b, p1);
    hipLaunchKernelGGL(conv2_pool, dim3(8192),  dim3(256),  0, stream, p1, c2w, c2b, seq);
    hipLaunchKernelGGL(ntm_scan6,  dim3(128),   dim3(1024), 0, stream,
                       seq, WG, hw2T, lb, hb, ow, ob, dw, db, out);
}

// Round 7
// 3800.851 us; speedup vs baseline: 1.8966x; 1.8966x over previous
//
#include <hip/hip_runtime.h>
#include <hip/hip_fp16.h>
#include <cstdint>
#include <cstddef>

// ---------------------------------------------------------------------------
// CNN (conv1+pool, conv2+pool) -> seq [256][256][32]
// NTM scan: 128 blocks x 1024 threads, 2 batch/block, 1 block/CU.
// Region-overlapped schedule per step i (4 barriers):
//  R1: waves 0..7: zA slice1 (pairs kq*36+0..11, 6 LDS-resident + 6 streamed)
//      waves 8..15: P3 head GEMM for step i-1 (2-way K split, coalesced)
//  R2: zA slice2 (12 streamed)  ||  P4 addressing (multi-wave) + e/a vectors
//  R3: zA slice3 (12 streamed)  ||  P5 fused read+erase/add -> rds + rp(fp16)
//  R4: LSTM (zpart sum + inline reads-contribution via 10 dot2 from rp/WrT)
// ci pair slots: [x:0..15][h:16..143]; reads enter z only through rp/WrT.
// ---------------------------------------------------------------------------

#define MW    20
#define NLOC  128
#define ZC    1024
#define PC    92
#define CLIPV 20.0f

__device__ __forceinline__ float sigmoidf_(float x) { return 1.0f / (1.0f + expf(-x)); }
__device__ __forceinline__ float softplusf_(float x) { return log1pf(expf(x)); }

__device__ __forceinline__ float dot2f(uint32_t w, uint32_t a, float c) {
    asm("v_dot2_f32_f16 %0, %1, %2, %0" : "+v"(c) : "v"(w), "v"(a));
    return c;
}

// weight row r (ci slot order) -> source
__device__ __forceinline__ float wval2(const float* wx, const float* wh, int r, int col) {
    if (r < 32)  return wx[r * ZC + col];                 // x rows
    if (r < 288) return wh[(r - 32) * ZC + col];          // h rows
    if (r < 308) return wx[(32 + (r - 288)) * ZC + col];  // reads rows
    return 0.0f;
}
__device__ __forceinline__ uint32_t packpr(const float* wx, const float* wh, int pr, int col) {
    __half2 h = __floats2half2_rn(wval2(wx, wh, 2 * pr, col), wval2(wx, wh, 2 * pr + 1, col));
    return *reinterpret_cast<uint32_t*>(&h);
}

// WA: u32 idx = ((pr*2 + j)*128 + c)*4 + m -> col = 8c + 4j + m, pr 0..143.
// WrT: [1024 cols][12] u32, q<10 = reads pair q at col, q>=10 zero.
// hw2: [128 up][92 col] u32 (col contiguous -> coalesced).
__global__ __launch_bounds__(256) void prep_pack(const float* __restrict__ wx,
                                                 const float* __restrict__ wh,
                                                 const float* __restrict__ hw,
                                                 uint32_t* __restrict__ WA,
                                                 uint32_t* __restrict__ WrT,
                                                 uint32_t* __restrict__ hw2) {
    int idx = blockIdx.x * 256 + threadIdx.x;
    if (idx < 147456) {
        int m = idx & 3, c = (idx >> 2) & 127, j = (idx >> 9) & 1, pr = idx >> 10;
        WA[idx] = packpr(wx, wh, pr, 8 * c + 4 * j + m);
    } else if (idx < 159744) {
        int q2 = idx - 147456;
        int col = q2 / 12, q = q2 - col * 12;
        WrT[q2] = (q < 10) ? packpr(wx, wh, 144 + q, col) : 0u;
    } else if (idx < 171520) {
        int q3 = idx - 159744;
        int up = q3 / 92, col = q3 - up * 92;
        __half2 h = __floats2half2_rn(hw[(2 * up) * PC + col], hw[(2 * up + 1) * PC + col]);
        hw2[q3] = *reinterpret_cast<uint32_t*>(&h);
    }
}

// conv1 3x3 (1->16) SAME + relu + maxpool2
__global__ __launch_bounds__(256) void conv1_pool(const float* __restrict__ in,
                                                  const float* __restrict__ w,
                                                  const float* __restrict__ bias,
                                                  float* __restrict__ out) {
    int idx = blockIdx.x * 256 + threadIdx.x;
    if (idx >= 256 * 32 * 32 * 16) return;
    int c = idx & 15, x = (idx >> 4) & 31, y = (idx >> 9) & 31, b = idx >> 14;
    const float* inb = in + (size_t)b * 4096;
    float bv = bias[c];
    float mx = 0.0f;
    #pragma unroll
    for (int dy = 0; dy < 2; ++dy)
    #pragma unroll
    for (int dx = 0; dx < 2; ++dx) {
        int oy = 2 * y + dy, ox = 2 * x + dx;
        float s = bv;
        #pragma unroll
        for (int ky = 0; ky < 3; ++ky) {
            int iy = oy + ky - 1;
            if (iy < 0 || iy > 63) continue;
            #pragma unroll
            for (int kx = 0; kx < 3; ++kx) {
                int ix = ox + kx - 1;
                if (ix < 0 || ix > 63) continue;
                s = fmaf(inb[iy * 64 + ix], w[(ky * 3 + kx) * 16 + c], s);
            }
        }
        mx = fmaxf(mx, fmaxf(s, 0.0f));
    }
    out[idx] = mx;
}

// conv2 3x3 (16->32) SAME + relu + maxpool2 (weights hoisted per tap, f4 inputs)
__global__ __launch_bounds__(256) void conv2_pool(const float* __restrict__ p1,
                                                  const float* __restrict__ w,
                                                  const float* __restrict__ bias,
                                                  float* __restrict__ seq) {
    int idx = blockIdx.x * 256 + threadIdx.x;
    if (idx >= 256 * 16 * 16 * 32) return;
    int c = idx & 31, x = (idx >> 5) & 15, y = (idx >> 9) & 15, b = idx >> 13;
    const float* pb = p1 + (size_t)b * (32 * 32 * 16);
    float bv = bias[c];
    float acc[4] = {bv, bv, bv, bv};
    #pragma unroll
    for (int ky = 0; ky < 3; ++ky)
    #pragma unroll
    for (int kx = 0; kx < 3; ++kx) {
        float w16[16];
        #pragma unroll
        for (int i = 0; i < 16; ++i) w16[i] = w[((ky * 3 + kx) * 16 + i) * 32 + c];
        #pragma unroll
        for (int dy = 0; dy < 2; ++dy)
        #pragma unroll
        for (int dx = 0; dx < 2; ++dx) {
            int iy = 2 * y + dy + ky - 1, ix = 2 * x + dx + kx - 1;
            if (iy < 0 || iy > 31 || ix < 0 || ix > 31) continue;
            const float4* pin4 = (const float4*)(pb + (iy * 32 + ix) * 16);
            float4 v0 = pin4[0], v1 = pin4[1], v2 = pin4[2], v3 = pin4[3];
            int a = dy * 2 + dx;
            acc[a] = fmaf(v0.x, w16[0], acc[a]);  acc[a] = fmaf(v0.y, w16[1], acc[a]);
            acc[a] = fmaf(v0.z, w16[2], acc[a]);  acc[a] = fmaf(v0.w, w16[3], acc[a]);
            acc[a] = fmaf(v1.x, w16[4], acc[a]);  acc[a] = fmaf(v1.y, w16[5], acc[a]);
            acc[a] = fmaf(v1.z, w16[6], acc[a]);  acc[a] = fmaf(v1.w, w16[7], acc[a]);
            acc[a] = fmaf(v2.x, w16[8], acc[a]);  acc[a] = fmaf(v2.y, w16[9], acc[a]);
            acc[a] = fmaf(v2.z, w16[10], acc[a]); acc[a] = fmaf(v2.w, w16[11], acc[a]);
            acc[a] = fmaf(v3.x, w16[12], acc[a]); acc[a] = fmaf(v3.y, w16[13], acc[a]);
            acc[a] = fmaf(v3.z, w16[14], acc[a]); acc[a] = fmaf(v3.w, w16[15], acc[a]);
        }
    }
    float mx = 0.0f;
    #pragma unroll
    for (int a = 0; a < 4; ++a) mx = fmaxf(mx, acc[a]);
    seq[idx] = mx;
}

// ---------------------------------------------------------------------------
// Persistent NTM scan, region-overlapped.
// ---------------------------------------------------------------------------
#define PS2(b_, col_) fminf(fmaxf(pp[0][b_][col_] + pp[1][b_][col_] + hb[col_], -CLIPV), CLIPV)

#define DOT16(w0_, w1_, a0_, a1_) \
    acc00 = dot2f(w0_.x, a0_, acc00); acc01 = dot2f(w0_.y, a0_, acc01); \
    acc02 = dot2f(w0_.z, a0_, acc02); acc03 = dot2f(w0_.w, a0_, acc03); \
    acc04 = dot2f(w1_.x, a0_, acc04); acc05 = dot2f(w1_.y, a0_, acc05); \
    acc06 = dot2f(w1_.z, a0_, acc06); acc07 = dot2f(w1_.w, a0_, acc07); \
    acc10 = dot2f(w0_.x, a1_, acc10); acc11 = dot2f(w0_.y, a1_, acc11); \
    acc12 = dot2f(w0_.z, a1_, acc12); acc13 = dot2f(w0_.w, a1_, acc13); \
    acc14 = dot2f(w1_.x, a1_, acc14); acc15 = dot2f(w1_.y, a1_, acc15); \
    acc16 = dot2f(w1_.z, a1_, acc16); acc17 = dot2f(w1_.w, a1_, acc17);

__global__ __launch_bounds__(1024, 4) void ntm_scan7(
    const float* __restrict__ seq,
    const uint32_t* __restrict__ WA,
    const uint32_t* __restrict__ WrT,
    const uint32_t* __restrict__ hw2G,
    const float* __restrict__ lb,
    const float* __restrict__ hb,
    const float* __restrict__ ow,
    const float* __restrict__ ob,
    const float* __restrict__ dw,
    const float* __restrict__ db,
    float* __restrict__ out)          // [256][2]
{
    __shared__ uint4 Wl4[24 * 2 * 128];               // 98304 B (6 pairs per kq)
    __shared__ float zpart[4][2][ZC];                 // 32768 B
    __shared__ __align__(16) _Float16 ci2h[2][288];   // 1152 B (x 0..31, h 32..287)
    __shared__ float Msh[2][MW][132];                 // 21120 B
    __shared__ float wprev[2][2][NLOC];               // 2048 B
    __shared__ float pp[2][2][PC];                    // 2944 B
    __shared__ float evs[2][MW], avs[2][MW];          // 320 B
    __shared__ float rds[2][MW];                      // 160 B
    __shared__ uint32_t rp[2][10];                    // 80 B
    __shared__ float o8[2][8];                        // 64 B
    // total 158960 B

    const int t = threadIdx.x;
    const int bs0 = blockIdx.x * 2;
    const int w = t >> 6;
    const uint4* WA4 = (const uint4*)WA;

    // ---- stage resident weights: for each kq, pairs kq*36 + 0..5 ----
    for (int i = t; i < 6144; i += 1024) {
        int c_ = i & 127, j_ = (i >> 7) & 1, pidx = i >> 8;
        int gpair = (pidx / 6) * 36 + (pidx % 6);
        Wl4[i] = WA4[(gpair * 2 + j_) * 128 + c_];
    }

    // ---- init state ----
    for (int i = t; i < 2 * 288; i += 1024) {
        int b = i / 288, k = i - b * 288;
        ci2h[b][k] = (k < 32) ? (_Float16)seq[(size_t)(bs0 + b) * 8192 + k] : (_Float16)0.0f;
    }
    for (int i = t; i < 2 * MW * 132; i += 1024) {
        int b = i / (MW * 132), r = i - b * (MW * 132);
        Msh[b][r / 132][r - (r / 132) * 132] = 1e-6f;
    }
    if (t < 512) {
        int b = t >> 8, r = t & 255;
        wprev[b][r >> 7][r & 127] = 1.0f / 128.0f;
    }
    if (t < 20) {
        __half2 h0 = __floats2half2_rn(1e-6f, 1e-6f);
        rp[t / 10][t % 10] = *reinterpret_cast<uint32_t*>(&h0);
    }
    float c_reg = 0.0f;   // cell state: thread t<512 owns (b=t>>8, u=t&255)
    __syncthreads();

    const uint32_t* ci2u0 = (const uint32_t*)&ci2h[0][0];
    const uint32_t* ci2u1 = (const uint32_t*)&ci2h[1][0];

    // ---- chainB phase bodies (waves 8..15 only) ----
    auto doP3 = [&]() {
        int tb = t - 512;
        if (tb < 368) {
            int kh = tb / 184, r = tb - kh * 184, b = r / 92, col = r - b * 92;
            const uint32_t* hu = (b ? ci2u1 : ci2u0) + 16 + kh * 64;
            const uint32_t* hp = hw2G + (kh * 64) * 92 + col;
            float s = 0.0f;
            #pragma unroll 8
            for (int uu = 0; uu < 64; ++uu) s = dot2f(hp[uu * 92], hu[uu], s);
            pp[kh][b][col] = s;
        }
    };
    auto doP4 = [&]() {
        int tb = t - 512;
        if (tb < 256) {
            const int l = tb & 63;
            const int b = tb >> 7, hh = (tb >> 6) & 1;
            const int hc = hh * 26;
            float beta  = softplusf_(PS2(b, hc + 20));
            float g     = sigmoidf_(PS2(b, hc + 21));
            float s0r = PS2(b, hc + 22), s1r = PS2(b, hc + 23), s2r = PS2(b, hc + 24);
            float mS = fmaxf(s0r, fmaxf(s1r, s2r));
            float q0 = expf(s0r - mS), q1 = expf(s1r - mS), q2 = expf(s2r - mS);
            float qin = 1.0f / (q0 + q1 + q2);
            float sh0 = q0 * qin, sh1 = q1 * qin, sh2 = q2 * qin;
            float gamma = softplusf_(PS2(b, hc + 25)) + 1.0f;

            float kvv = (l < 20) ? tanhf(PS2(b, hc + l)) : 0.0f;
            float kn2 = kvv * kvv;
            #pragma unroll
            for (int o = 1; o < 64; o <<= 1) kn2 += __shfl_xor(kn2, o, 64);
            float kden = sqrtf(kn2) + 1e-8f;

            float d0 = 0, d1 = 0, m20 = 0, m21 = 0;
            #pragma unroll
            for (int wi = 0; wi < 20; ++wi) {
                float kk = __shfl(kvv, wi, 64);
                float2 mv = *reinterpret_cast<const float2*>(&Msh[b][wi][2 * l]);
                d0  = fmaf(kk, mv.x, d0);      d1  = fmaf(kk, mv.y, d1);
                m20 = fmaf(mv.x, mv.x, m20);   m21 = fmaf(mv.y, mv.y, m21);
            }
            float x0 = beta * (d0 / ((sqrtf(m20) + 1e-8f) * kden));
            float x1 = beta * (d1 / ((sqrtf(m21) + 1e-8f) * kden));
            float mx = fmaxf(x0, x1);
            #pragma unroll
            for (int o = 1; o < 64; o <<= 1) mx = fmaxf(mx, __shfl_xor(mx, o, 64));
            float e0 = expf(x0 - mx), e1 = expf(x1 - mx);
            float se = e0 + e1;
            #pragma unroll
            for (int o = 1; o < 64; o <<= 1) se += __shfl_xor(se, o, 64);
            float inv = 1.0f / se;
            float2 wpv = *reinterpret_cast<const float2*>(&wprev[b][hh][2 * l]);
            float wg0 = g * (e0 * inv) + (1.0f - g) * wpv.x;
            float wg1 = g * (e1 * inv) + (1.0f - g) * wpv.y;
            float wgm = __shfl(wg1, (l + 63) & 63, 64);
            float wgp = __shfl(wg0, (l + 1) & 63, 64);
            float wt0 = sh0 * wg1 + sh1 * wg0 + sh2 * wgm;
            float wt1 = sh0 * wgp + sh1 * wg1 + sh2 * wg0;
            float wpw0 = expf(gamma * logf(wt0 + 1e-8f));
            float wpw1 = expf(gamma * logf(wt1 + 1e-8f));
            float ssum = wpw0 + wpw1;
            #pragma unroll
            for (int o = 1; o < 64; o <<= 1) ssum += __shfl_xor(ssum, o, 64);
            float rin = 1.0f / ssum;
            *reinterpret_cast<float2*>(&wprev[b][hh][2 * l]) = make_float2(wpw0 * rin, wpw1 * rin);
        } else if (tb < 336) {
            int q = tb - 256, b = q / 40, r2 = q - b * 40;
            if (r2 < 20) evs[b][r2]      = sigmoidf_(PS2(b, 52 + r2));
            else         avs[b][r2 - 20] = tanhf(PS2(b, 72 + (r2 - 20)));
        }
    };
    auto doP5 = [&]() {
        int tb = t - 512;
        if (tb < 320) {
            int grp = tb >> 4;                 // (b, q) 16-lane group
            int b = grp / 10, q = grp - b * 10;
            int half = (tb >> 3) & 1, l8 = tb & 7;
            int wi = 2 * q + half;
            int n0 = l8 * 16;
            float evb = evs[b][wi], avb = avs[b][wi];
            float s = 0.0f;
            #pragma unroll
            for (int n = n0; n < n0 + 16; ++n) {
                float m = Msh[b][wi][n];
                s = fmaf(wprev[b][0][n], m, s);
                float ww = wprev[b][1][n];
                Msh[b][wi][n] = m * (1.0f - ww * evb) + ww * avb;
            }
            s += __shfl_xor(s, 1, 64); s += __shfl_xor(s, 2, 64); s += __shfl_xor(s, 4, 64);
            float rodd = __shfl_xor(s, 8, 64);
            if ((tb & 15) == 0) {
                rds[b][2 * q] = s; rds[b][2 * q + 1] = rodd;
                __half2 hp = __floats2half2_rn(s, rodd);
                rp[b][q] = *reinterpret_cast<uint32_t*>(&hp);
            }
        }
    };

    const int kq = t >> 7, c = t & 127;       // chainA decomposition (t < 512)
    const int prb = kq * 36;

    for (int step = 0; step < 256; ++step) {
        float acc00, acc01, acc02, acc03, acc04, acc05, acc06, acc07;
        float acc10, acc11, acc12, acc13, acc14, acc15, acc16, acc17;

        // ---- R1 ----
        if (w < 8) {
            acc00 = acc01 = acc02 = acc03 = acc04 = acc05 = acc06 = acc07 = 0.0f;
            acc10 = acc11 = acc12 = acc13 = acc14 = acc15 = acc16 = acc17 = 0.0f;
            #pragma unroll
            for (int p = 0; p < 6; ++p) {
                int pr = prb + p;
                uint4 w0 = Wl4[((kq * 6 + p) * 2 + 0) * 128 + c];
                uint4 w1 = Wl4[((kq * 6 + p) * 2 + 1) * 128 + c];
                uint32_t a0 = ci2u0[pr], a1 = ci2u1[pr];
                DOT16(w0, w1, a0, a1)
            }
            #pragma unroll
            for (int p = 6; p < 12; ++p) {
                int pr = prb + p;
                uint4 w0 = WA4[(pr * 2 + 0) * 128 + c];
                uint4 w1 = WA4[(pr * 2 + 1) * 128 + c];
                uint32_t a0 = ci2u0[pr], a1 = ci2u1[pr];
                DOT16(w0, w1, a0, a1)
            }
        } else if (step > 0) doP3();
        __syncthreads();   // B1

        // ---- R2 ----
        if (w < 8) {
            #pragma unroll
            for (int p = 12; p < 24; ++p) {
                int pr = prb + p;
                uint4 w0 = WA4[(pr * 2 + 0) * 128 + c];
                uint4 w1 = WA4[(pr * 2 + 1) * 128 + c];
                uint32_t a0 = ci2u0[pr], a1 = ci2u1[pr];
                DOT16(w0, w1, a0, a1)
            }
        } else if (step > 0) doP4();
        __syncthreads();   // B2

        // ---- R3 ----
        if (w < 8) {
            #pragma unroll
            for (int p = 24; p < 36; ++p) {
                int pr = prb + p;
                uint4 w0 = WA4[(pr * 2 + 0) * 128 + c];
                uint4 w1 = WA4[(pr * 2 + 1) * 128 + c];
                uint32_t a0 = ci2u0[pr], a1 = ci2u1[pr];
                DOT16(w0, w1, a0, a1)
            }
            *(float4*)&zpart[kq][0][8 * c]     = make_float4(acc00, acc01, acc02, acc03);
            *(float4*)&zpart[kq][0][8 * c + 4] = make_float4(acc04, acc05, acc06, acc07);
            *(float4*)&zpart[kq][1][8 * c]     = make_float4(acc10, acc11, acc12, acc13);
            *(float4*)&zpart[kq][1][8 * c + 4] = make_float4(acc14, acc15, acc16, acc17);
        } else if (step > 0) doP5();
        __syncthreads();   // B3

        // ---- R4: LSTM with inline reads-contribution ----
        if (t < 512) {
            int b = t >> 8, u = t & 255;
            uint32_t rp0 = rp[b][0], rp1 = rp[b][1], rp2 = rp[b][2], rp3 = rp[b][3];
            uint32_t rp4 = rp[b][4], rp5 = rp[b][5], rp6 = rp[b][6], rp7 = rp[b][7];
            uint32_t rp8 = rp[b][8], rp9 = rp[b][9];
            float zg4[4];
            #pragma unroll
            for (int g4 = 0; g4 < 4; ++g4) {
                const uint4* wp = (const uint4*)(WrT + ((g4 << 8) + u) * 12);
                uint4 A = wp[0], B = wp[1], C = wp[2];
                float s = 0.0f;
                s = dot2f(A.x, rp0, s); s = dot2f(A.y, rp1, s);
                s = dot2f(A.z, rp2, s); s = dot2f(A.w, rp3, s);
                s = dot2f(B.x, rp4, s); s = dot2f(B.y, rp5, s);
                s = dot2f(B.z, rp6, s); s = dot2f(B.w, rp7, s);
                s = dot2f(C.x, rp8, s); s = dot2f(C.y, rp9, s);
                zg4[g4] = s;
            }
            float zi = lb[u]       + zg4[0] + zpart[0][b][u]       + zpart[1][b][u]       + zpart[2][b][u]       + zpart[3][b][u];
            float zf = lb[256 + u] + zg4[1] + zpart[0][b][256 + u] + zpart[1][b][256 + u] + zpart[2][b][256 + u] + zpart[3][b][256 + u];
            float zg = lb[512 + u] + zg4[2] + zpart[0][b][512 + u] + zpart[1][b][512 + u] + zpart[2][b][512 + u] + zpart[3][b][512 + u];
            float zo = lb[768 + u] + zg4[3] + zpart[0][b][768 + u] + zpart[1][b][768 + u] + zpart[2][b][768 + u] + zpart[3][b][768 + u];
            float cg = sigmoidf_(zf) * c_reg + sigmoidf_(zi) * tanhf(zg);
            c_reg = cg;
            ci2h[b][32 + u] = (_Float16)(sigmoidf_(zo) * tanhf(cg));
        } else if (t < 576 && step < 255) {
            int q = t - 512, b = q >> 5, cc = q & 31;
            ci2h[b][cc] = (_Float16)seq[(size_t)(bs0 + b) * 8192 + (size_t)(step + 1) * 32 + cc];
        }
        __syncthreads();   // B4
    }

    // ---- epilogue: step-255 memory chain ----
    if (w >= 8) doP3();
    __syncthreads();
    if (w >= 8) doP4();
    __syncthreads();
    if (w >= 8) doP5();
    __syncthreads();

    // ---- final NTM output head + dense + softmax ----
    if (t < 16) {
        int b = t >> 3, o = t & 7;
        float s = ob[o];
        for (int u = 0; u < 256; ++u) s = fmaf((float)ci2h[b][32 + u], ow[u * 8 + o], s);
        #pragma unroll
        for (int wi = 0; wi < 20; ++wi) s = fmaf(rds[b][wi], ow[(256 + wi) * 8 + o], s);
        o8[b][o] = fminf(fmaxf(s, -CLIPV), CLIPV);
    }
    __syncthreads();
    if (t < 2) {
        float l0 = db[0], l1 = db[1];
        #pragma unroll
        for (int k = 0; k < 8; ++k) {
            float v = o8[t][k];
            l0 = fmaf(v, dw[k * 2 + 0], l0);
            l1 = fmaf(v, dw[k * 2 + 1], l1);
        }
        float m = fmaxf(l0, l1);
        float q0 = expf(l0 - m), q1 = expf(l1 - m);
        float inv = 1.0f / (q0 + q1);
        out[(bs0 + t) * 2 + 0] = q0 * inv;
        out[(bs0 + t) * 2 + 1] = q1 * inv;
    }
}

extern "C" void kernel_launch(void* const* d_in, const int* in_sizes, int n_in,
                              void* d_out, int out_size, void* d_ws, size_t ws_size,
                              hipStream_t stream) {
    const float* inputs = (const float*)d_in[0];
    const float* c1w = (const float*)d_in[1];
    const float* c1b = (const float*)d_in[2];
    const float* c2w = (const float*)d_in[3];
    const float* c2b = (const float*)d_in[4];
    const float* lwx = (const float*)d_in[5];
    const float* lwh = (const float*)d_in[6];
    const float* lb  = (const float*)d_in[7];
    const float* hw  = (const float*)d_in[8];
    const float* hb  = (const float*)d_in[9];
    const float* ow  = (const float*)d_in[10];
    const float* ob  = (const float*)d_in[11];
    const float* dw  = (const float*)d_in[12];
    const float* db  = (const float*)d_in[13];
    float* out = (float*)d_out;

    float* ws  = (float*)d_ws;
    float* p1  = ws;                             // 4,194,304 f
    float* seq = ws + 4194304;                   // 2,097,152 f
    uint32_t* WA   = (uint32_t*)(ws + 6291456);  // 147,456 u32
    uint32_t* WrT  = WA + 147456;                //  12,288 u32
    uint32_t* hw2G = WrT + 12288;                //  11,776 u32

    hipLaunchKernelGGL(prep_pack,  dim3(670),   dim3(256),  0, stream, lwx, lwh, hw, WA, WrT, hw2G);
    hipLaunchKernelGGL(conv1_pool, dim3(16384), dim3(256),  0, stream, inputs, c1w, c1b, p1);
    hipLaunchKernelGGL(conv2_pool, dim3(8192),  dim3(256),  0, stream, p1, c2w, c2b, seq);
    hipLaunchKernelGGL(ntm_scan7,  dim3(128),   dim3(1024), 0, stream,
                       seq, WA, WrT, hw2G, lb, hb, ow, ob, dw, db, out);
}